// Round 1
// baseline (221.500 us; speedup 1.0000x reference)
//
#include <hip/hip_runtime.h>

// OrdinalRegressionLoss: mean over (B,4) of
//   max(x,0) - x*y + log1p(exp(-|x|)),  y[i][j] = (j < targets[i])
// B = 8388608, T = 4. Memory-bound streaming reduction (~168 MB in, 4 B out).

#define NROWS 8388608
#define NTHR 4

__device__ __forceinline__ float bce_term(float x, int j, int tgt) {
    // max(x,0) - x*y + log(1 + exp(-|x|))
    float y = (j < tgt) ? 1.0f : 0.0f;
    return fmaxf(x, 0.0f) - x * y + __logf(1.0f + __expf(-fabsf(x)));
}

__global__ __launch_bounds__(256) void ord_loss_reduce(
        const float4* __restrict__ logits4,   // (B) rows of 4 floats
        const int* __restrict__ targets,
        double* __restrict__ ws_sum,
        int nrows) {
    int tid = blockIdx.x * blockDim.x + threadIdx.x;
    int stride = gridDim.x * blockDim.x;

    float acc = 0.0f;
    for (int i = tid; i < nrows; i += stride) {
        float4 x = logits4[i];       // 16 B/lane, coalesced
        int t = targets[i];          // 4 B/lane, coalesced
        acc += bce_term(x.x, 0, t);
        acc += bce_term(x.y, 1, t);
        acc += bce_term(x.z, 2, t);
        acc += bce_term(x.w, 3, t);
    }

    // wave-64 butterfly reduce
    #pragma unroll
    for (int off = 32; off > 0; off >>= 1)
        acc += __shfl_down(acc, off, 64);

    __shared__ float wsum[4];        // 256 threads = 4 waves
    int lane = threadIdx.x & 63;
    int wid  = threadIdx.x >> 6;
    if (lane == 0) wsum[wid] = acc;
    __syncthreads();

    if (threadIdx.x == 0) {
        float s = wsum[0] + wsum[1] + wsum[2] + wsum[3];
        atomicAdd(ws_sum, (double)s);   // device-scope, cross-XCD safe
    }
}

__global__ void ord_loss_final(const double* __restrict__ ws_sum,
                               float* __restrict__ out) {
    out[0] = (float)(ws_sum[0] * (1.0 / ((double)NROWS * (double)NTHR)));
}

extern "C" void kernel_launch(void* const* d_in, const int* in_sizes, int n_in,
                              void* d_out, int out_size, void* d_ws, size_t ws_size,
                              hipStream_t stream) {
    const float4* logits = (const float4*)d_in[0];
    const int* targets = (const int*)d_in[1];
    double* ws_sum = (double*)d_ws;
    float* out = (float*)d_out;

    // d_ws is poisoned to 0xAA before every timed launch — zero the accumulator.
    hipMemsetAsync(ws_sum, 0, sizeof(double), stream);

    int nrows = NROWS;
    int block = 256;
    int grid = 2048;     // 524288 threads -> 16 rows/thread grid-stride
    ord_loss_reduce<<<grid, block, 0, stream>>>(logits, targets, ws_sum, nrows);
    ord_loss_final<<<1, 1, 0, stream>>>(ws_sum, out);
}

// Round 2
// 211.986 us; speedup vs baseline: 1.0449x; 1.0449x over previous
//
#include <hip/hip_runtime.h>

// OrdinalRegressionLoss: mean over (B,4) of
//   max(x,0) - x*y + log1p(exp(-|x|)),  y[i][j] = (j < targets[i])
// B = 8388608, T = 4. Memory-bound streaming reduction:
// 134 MB logits (f32) + 33.5 MB targets (i32) read, 4 B out.
// Roofline: ~168 MB / 6.3 TB/s ≈ 27 µs for the reduce kernel.

#define NROWS 8388608
#define NTHR  4
#define BLOCK 256
#define GRID  2048
#define NTHREADS (BLOCK * GRID)      // 524288
#define RPT   (NROWS / NTHREADS)     // 16 rows/thread, exact

__device__ __forceinline__ float row_loss(float4 x, int t) {
    // per-threshold stable BCE: max(x,0) + log(1+exp(-|x|)) - x*(j<t)
    float s0 = fmaxf(x.x, 0.f) + __logf(1.f + __expf(-fabsf(x.x))) - (t > 0 ? x.x : 0.f);
    float s1 = fmaxf(x.y, 0.f) + __logf(1.f + __expf(-fabsf(x.y))) - (t > 1 ? x.y : 0.f);
    float s2 = fmaxf(x.z, 0.f) + __logf(1.f + __expf(-fabsf(x.z))) - (t > 2 ? x.z : 0.f);
    float s3 = fmaxf(x.w, 0.f) + __logf(1.f + __expf(-fabsf(x.w))) - (t > 3 ? x.w : 0.f);
    return (s0 + s1) + (s2 + s3);
}

__global__ __launch_bounds__(BLOCK) void ord_loss_reduce(
        const float4* __restrict__ logits4,   // NROWS rows of 4 floats
        const int*    __restrict__ targets,
        float*        __restrict__ partials) { // GRID floats, write-only
    const int tid = blockIdx.x * BLOCK + threadIdx.x;

    float acc = 0.0f;
    // 4 chunks x 4 rows: within a chunk all 8 loads (4 float4 + 4 int)
    // are independent -> in flight together; lanes stay unit-stride.
    #pragma unroll
    for (int c = 0; c < RPT / 4; ++c) {
        const int i0 = tid + (4 * c + 0) * NTHREADS;
        const int i1 = tid + (4 * c + 1) * NTHREADS;
        const int i2 = tid + (4 * c + 2) * NTHREADS;
        const int i3 = tid + (4 * c + 3) * NTHREADS;
        float4 x0 = logits4[i0];
        float4 x1 = logits4[i1];
        float4 x2 = logits4[i2];
        float4 x3 = logits4[i3];
        int t0 = targets[i0];
        int t1 = targets[i1];
        int t2 = targets[i2];
        int t3 = targets[i3];
        acc += row_loss(x0, t0);
        acc += row_loss(x1, t1);
        acc += row_loss(x2, t2);
        acc += row_loss(x3, t3);
    }

    // wave-64 butterfly reduce
    #pragma unroll
    for (int off = 32; off > 0; off >>= 1)
        acc += __shfl_down(acc, off, 64);

    __shared__ float wsum[BLOCK / 64];
    const int lane = threadIdx.x & 63;
    const int wid  = threadIdx.x >> 6;
    if (lane == 0) wsum[wid] = acc;
    __syncthreads();

    if (threadIdx.x == 0)
        partials[blockIdx.x] = (wsum[0] + wsum[1]) + (wsum[2] + wsum[3]);
}

__global__ __launch_bounds__(BLOCK) void ord_loss_final(
        const float* __restrict__ partials,
        float*       __restrict__ out) {
    // 2048 partials, 256 threads -> 8 each, coalesced
    double a = 0.0;
    #pragma unroll
    for (int k = 0; k < GRID / BLOCK; ++k)
        a += (double)partials[threadIdx.x + k * BLOCK];

    #pragma unroll
    for (int off = 32; off > 0; off >>= 1)
        a += __shfl_down(a, off, 64);

    __shared__ double wsum[BLOCK / 64];
    const int lane = threadIdx.x & 63;
    const int wid  = threadIdx.x >> 6;
    if (lane == 0) wsum[wid] = a;
    __syncthreads();

    if (threadIdx.x == 0) {
        double total = (wsum[0] + wsum[1]) + (wsum[2] + wsum[3]);
        out[0] = (float)(total / ((double)NROWS * (double)NTHR));
    }
}

extern "C" void kernel_launch(void* const* d_in, const int* in_sizes, int n_in,
                              void* d_out, int out_size, void* d_ws, size_t ws_size,
                              hipStream_t stream) {
    const float4* logits = (const float4*)d_in[0];
    const int* targets = (const int*)d_in[1];
    float* partials = (float*)d_ws;   // write-only: poison-safe, no memset needed
    float* out = (float*)d_out;

    ord_loss_reduce<<<GRID, BLOCK, 0, stream>>>(logits, targets, partials);
    ord_loss_final<<<1, BLOCK, 0, stream>>>(partials, out);
}